// Round 1
// 495.024 us; speedup vs baseline: 3.1442x; 3.1442x over previous
//
#include <hip/hip_runtime.h>
#include <math.h>

#define C_DIM  512   // channels (K of the dot product)
#define N_DICT 512   // dictionary rows
#define HW     4096  // 64*64 pixels per image

typedef _Float16 h8_t __attribute__((ext_vector_type(8)));
typedef _Float16 h4_t __attribute__((ext_vector_type(4)));
typedef float    f4_t __attribute__((ext_vector_type(4)));

#define SCALE_D 16384.0f   // keeps fp16 low-half of dict out of subnormal range
#define SCALE_X 256.0f     // same for x

// ---------------------------------------------------------------------------
// Prologue: inv_norm (scale-folded) + two-way fp16 split of dict (x2^14).
// d = (d1 + d2)/2^14 with |err| <= 2^-24 |d|.
// ---------------------------------------------------------------------------
__global__ __launch_bounds__(64) void dict_prep(const float* __restrict__ dict,
                                                _Float16* __restrict__ d1,
                                                _Float16* __restrict__ d2,
                                                float* __restrict__ invn) {
    const int n = blockIdx.x;
    const int lane = threadIdx.x;
    const float* __restrict__ row = dict + n * C_DIM;
    const float4* rp = (const float4*)(row + lane * 8);
    float4 va = rp[0], vb = rp[1];
    float vv[8] = {va.x, va.y, va.z, va.w, vb.x, vb.y, vb.z, vb.w};
    float s = 0.f;
    h8_t h1, h2;
#pragma unroll
    for (int j = 0; j < 8; ++j) {
        float v = vv[j];
        s = fmaf(v, v, s);
        float xs = v * SCALE_D;
        _Float16 a = (_Float16)xs;
        float r = xs - (float)a;
        h1[j] = a;
        h2[j] = (_Float16)r;
    }
    *(h8_t*)(d1 + n * C_DIM + lane * 8) = h1;
    *(h8_t*)(d2 + n * C_DIM + lane * 8) = h2;
#pragma unroll
    for (int off = 32; off > 0; off >>= 1) s += __shfl_down(s, off, 64);
    if (lane == 0) invn[n] = (1.0f / sqrtf(s)) * (1.0f / (SCALE_D * SCALE_X));
}

// ---------------------------------------------------------------------------
// Main MFMA kernel. Grid 1024 = 16 batches x 64 pixel-groups; 512 thr (8 waves).
// Block: 64 pixels, all 512 dict rows (wave w -> rows [64w, 64w+64)).
// Per wave per 32-channel K-step: 8 global A-loads (L2-hot split dict),
// 8 ds_read_b128 B-frags, 48 mfma_f32_16x16x32_f16 (3-product fp32 emulation).
// x tile double-buffered in LDS, fp16-split during staging; sumsq rides along.
// ---------------------------------------------------------------------------
__global__ __launch_bounds__(512, 2) void negdict_mfma(
        const float* __restrict__ x,
        const float* __restrict__ dict,
        const _Float16* __restrict__ d1,
        const _Float16* __restrict__ d2,
        const float* __restrict__ invn,
        float* __restrict__ out) {
    // [buf][pixel(64)][128 B]: per-pixel row = 4 k-blocks x 2 splits x 8 fp16,
    // 16B slot index (kb*2+s) XOR'd with (pix&7) -> conflict-free-minimum b128.
    __shared__ __attribute__((aligned(16))) unsigned char lds_x[2][64 * 128];
    __shared__ float ls_best[8][64];
    __shared__ int   ls_idx[8][64];
    __shared__ float ls_ssq[8][64];
    __shared__ int   fin[64];

    const int pg   = blockIdx.x;
    const int b    = pg >> 6;
    const int pix0 = (pg & 63) << 6;
    const int t    = (int)threadIdx.x;
    const int lane = t & 63;
    const int w    = __builtin_amdgcn_readfirstlane(t >> 6); // 0..7 uniform

    const float* __restrict__ xb = x + (size_t)b * (C_DIM * HW);

    // staging: thread (w, lane) loads channels kc+4w..kc+4w+3 of pixel `lane`
    const int kb  = w >> 1;  // 8-wide k-block 0..3
    const int kh  = w & 1;   // half within the 16B slot
    const int wr0 = lane * 128 + (((kb * 2 + 0) ^ (lane & 7)) * 16) + kh * 8;
    const int wr1 = lane * 128 + (((kb * 2 + 1) ^ (lane & 7)) * 16) + kh * 8;

    float sumsq = 0.f;

    // A-frag addressing: lane holds A[row = lane&15][k = 8*(lane>>4)+j]
    const int arow = lane & 15;
    const int akq  = lane >> 4;
    const _Float16* __restrict__ a1b = d1 + (size_t)(w * 64 + arow) * C_DIM + 8 * akq;
    const _Float16* __restrict__ a2b = d2 + (size_t)(w * 64 + arow) * C_DIM + 8 * akq;

    // B-frag LDS offsets: lane holds B[k = 8*(lane>>4)+j][pix = cf*16 + (lane&15)]
    int rdo[4][2];
#pragma unroll
    for (int cf = 0; cf < 4; ++cf) {
#pragma unroll
        for (int s = 0; s < 2; ++s) {
            int p = cf * 16 + (lane & 15);
            int slot = ((lane >> 4) * 2 + s) ^ (p & 7);
            rdo[cf][s] = p * 128 + slot * 16;
        }
    }

    f4_t acc[4][4];
#pragma unroll
    for (int rf = 0; rf < 4; ++rf)
#pragma unroll
        for (int cf = 0; cf < 4; ++cf)
            acc[rf][cf] = (f4_t){0.f, 0.f, 0.f, 0.f};

    // stage K-step 0 into buf 0
    {
        const float* xp = xb + (size_t)(4 * w) * HW + pix0 + lane;
        float xvv[4] = {xp[0], xp[HW], xp[2 * HW], xp[3 * HW]};
        h4_t p1, p2;
#pragma unroll
        for (int i = 0; i < 4; ++i) {
            float v = xvv[i];
            sumsq = fmaf(v, v, sumsq);
            float xs = v * SCALE_X;
            _Float16 a = (_Float16)xs;
            float r = xs - (float)a;
            p1[i] = a;
            p2[i] = (_Float16)r;
        }
        *(h4_t*)(&lds_x[0][wr0]) = p1;
        *(h4_t*)(&lds_x[0][wr1]) = p2;
    }
    __syncthreads();

    int cur = 0;
#pragma unroll 1
    for (int step = 0; step < 16; ++step) {
        const int kc = step * 32;

        // issue next tile's x loads early (hide HBM latency under MFMAs)
        float nxt0 = 0.f, nxt1 = 0.f, nxt2 = 0.f, nxt3 = 0.f;
        if (step < 15) {
            const float* xp = xb + (size_t)(kc + 32 + 4 * w) * HW + pix0 + lane;
            nxt0 = xp[0]; nxt1 = xp[HW]; nxt2 = xp[2 * HW]; nxt3 = xp[3 * HW];
        }

        h8_t A1[4], A2[4], B1[4], B2[4];
#pragma unroll
        for (int rf = 0; rf < 4; ++rf) {
            A1[rf] = *(const h8_t*)(a1b + rf * (16 * C_DIM) + kc);
            A2[rf] = *(const h8_t*)(a2b + rf * (16 * C_DIM) + kc);
        }
        const unsigned char* lb = lds_x[cur];
#pragma unroll
        for (int cf = 0; cf < 4; ++cf) {
            B1[cf] = *(const h8_t*)(lb + rdo[cf][0]);
            B2[cf] = *(const h8_t*)(lb + rdo[cf][1]);
        }

#pragma unroll
        for (int rf = 0; rf < 4; ++rf) {
#pragma unroll
            for (int cf = 0; cf < 4; ++cf) {
                acc[rf][cf] = __builtin_amdgcn_mfma_f32_16x16x32_f16(A1[rf], B1[cf], acc[rf][cf], 0, 0, 0);
                acc[rf][cf] = __builtin_amdgcn_mfma_f32_16x16x32_f16(A1[rf], B2[cf], acc[rf][cf], 0, 0, 0);
                acc[rf][cf] = __builtin_amdgcn_mfma_f32_16x16x32_f16(A2[rf], B1[cf], acc[rf][cf], 0, 0, 0);
            }
        }

        if (step < 15) {
            unsigned char* lw = lds_x[cur ^ 1];
            float xvv[4] = {nxt0, nxt1, nxt2, nxt3};
            h4_t p1, p2;
#pragma unroll
            for (int i = 0; i < 4; ++i) {
                float v = xvv[i];
                sumsq = fmaf(v, v, sumsq);
                float xs = v * SCALE_X;
                _Float16 a = (_Float16)xs;
                float r = xs - (float)a;
                p1[i] = a;
                p2[i] = (_Float16)r;
            }
            *(h4_t*)(lw + wr0) = p1;
            *(h4_t*)(lw + wr1) = p2;
        }
        __syncthreads();
        cur ^= 1;
    }

    // ---- per-pixel argmax: lane holds rows rbase + 16rf + i for 4 cf-pixels
    float best0 = -3.0e38f, best1 = -3.0e38f, best2 = -3.0e38f, best3 = -3.0e38f;
    int bi0 = 0, bi1 = 0, bi2 = 0, bi3 = 0;
    const int rbase = w * 64 + akq * 4;   // D row = (lane>>4)*4 + i  (+16rf +n0)
#pragma unroll
    for (int rf = 0; rf < 4; ++rf) {
#pragma unroll
        for (int i = 0; i < 4; ++i) {
            const int row = rbase + rf * 16 + i;
            const float inv = invn[row];
            float v0 = acc[rf][0][i] * inv;
            float v1 = acc[rf][1][i] * inv;
            float v2 = acc[rf][2][i] * inv;
            float v3 = acc[rf][3][i] * inv;
            if (v0 > best0 || (v0 == best0 && row < bi0)) { best0 = v0; bi0 = row; }
            if (v1 > best1 || (v1 == best1 && row < bi1)) { best1 = v1; bi1 = row; }
            if (v2 > best2 || (v2 == best2 && row < bi2)) { best2 = v2; bi2 = row; }
            if (v3 > best3 || (v3 == best3 && row < bi3)) { best3 = v3; bi3 = row; }
        }
    }
    // reduce across the 4 lane-groups sharing each pixel (xor 16, 32)
#pragma unroll
    for (int off = 16; off <= 32; off <<= 1) {
        float o0 = __shfl_xor(best0, off, 64); int m0 = __shfl_xor(bi0, off, 64);
        float o1 = __shfl_xor(best1, off, 64); int m1 = __shfl_xor(bi1, off, 64);
        float o2 = __shfl_xor(best2, off, 64); int m2 = __shfl_xor(bi2, off, 64);
        float o3 = __shfl_xor(best3, off, 64); int m3 = __shfl_xor(bi3, off, 64);
        if (o0 > best0 || (o0 == best0 && m0 < bi0)) { best0 = o0; bi0 = m0; }
        if (o1 > best1 || (o1 == best1 && m1 < bi1)) { best1 = o1; bi1 = m1; }
        if (o2 > best2 || (o2 == best2 && m2 < bi2)) { best2 = o2; bi2 = m2; }
        if (o3 > best3 || (o3 == best3 && m3 < bi3)) { best3 = o3; bi3 = m3; }
    }
    if (akq == 0) {   // lanes 0..15 publish per-wave winners
        ls_best[w][ 0 + arow] = best0; ls_idx[w][ 0 + arow] = bi0;
        ls_best[w][16 + arow] = best1; ls_idx[w][16 + arow] = bi1;
        ls_best[w][32 + arow] = best2; ls_idx[w][32 + arow] = bi2;
        ls_best[w][48 + arow] = best3; ls_idx[w][48 + arow] = bi3;
    }
    ls_ssq[w][lane] = sumsq;   // thread covered channels {4w..} quarter of pixel `lane`
    __syncthreads();

    if (t < 64) {
        const int p = t;
        float fb = ls_best[0][p]; int fi = ls_idx[0][p];
#pragma unroll
        for (int q = 1; q < 8; ++q) {
            float v = ls_best[q][p]; int id = ls_idx[q][p];
            if (v > fb || (v == fb && id < fi)) { fb = v; fi = id; }
        }
        float ss = 0.f;
#pragma unroll
        for (int q = 0; q < 8; ++q) ss += ls_ssq[q][p];
        // apm < 0.625  <=>  sim > -0.25  <=>  fb > -0.25*||x||   (scales folded)
        fin[p] = (fb > (-0.25f * sqrtf(ss))) ? fi : -1;
    }
    __syncthreads();

    // ---- write-out: wave w owns channels [64w, 64w+64)
    const int fi = fin[lane];
    const bool rep = fi >= 0;
    const unsigned long long need_x = __ballot(!rep);  // almost always 0
    const float* __restrict__ drow = dict + (size_t)(rep ? fi : 0) * C_DIM;
    float* __restrict__ ob = out + (size_t)b * (C_DIM * HW) + pix0 + lane;
    const int c0 = w * 64;
#pragma unroll 8
    for (int c = c0; c < c0 + 64; ++c) {
        float v = drow[c];                 // per-lane gather, dict L2-hot
        if (need_x) {
            float xv = xb[(size_t)c * HW + pix0 + lane];
            if (!rep) v = xv;
        }
        ob[(size_t)c * HW] = v;            // coalesced store
    }
}

// ---------------------------------------------------------------------------
// Fallback path (verified 1556 us kernel) in case workspace is too small for
// the split-dict arrays.
// ---------------------------------------------------------------------------
__global__ __launch_bounds__(64) void dict_inv_norm(const float* __restrict__ dict,
                                                    float* __restrict__ inv_norm) {
    const int n = blockIdx.x;
    const int lane = threadIdx.x;
    const float* row = dict + n * C_DIM;
    float s = 0.f;
#pragma unroll
    for (int j = 0; j < C_DIM / 64; ++j) {
        float v = row[j * 64 + lane];
        s = fmaf(v, v, s);
    }
#pragma unroll
    for (int off = 32; off > 0; off >>= 1)
        s += __shfl_down(s, off, 64);
    if (lane == 0) inv_norm[n] = 1.0f / sqrtf(s);
}

#define ACCS(F) F(0) F(1) F(2) F(3) F(4) F(5) F(6) F(7) \
                F(8) F(9) F(10) F(11) F(12) F(13) F(14) F(15) \
                F(16) F(17) F(18) F(19) F(20) F(21) F(22) F(23) \
                F(24) F(25) F(26) F(27) F(28) F(29) F(30) F(31)

#define DECL_ACC(i) float acc##i = 0.f;

#define ROW_FMA(i) { const float* __restrict__ dr = dbase + (size_t)(i) * C_DIM; \
    acc##i = fmaf(dr[0], xk0, acc##i); \
    acc##i = fmaf(dr[1], xk1, acc##i); \
    acc##i = fmaf(dr[2], xk2, acc##i); \
    acc##i = fmaf(dr[3], xk3, acc##i); \
    acc##i = fmaf(dr[4], xk4, acc##i); \
    acc##i = fmaf(dr[5], xk5, acc##i); \
    acc##i = fmaf(dr[6], xk6, acc##i); \
    acc##i = fmaf(dr[7], xk7, acc##i); }

#define ARGMAX(i) { float s = acc##i * invn[i]; \
    if (s > best) { best = s; bestn = n0 + (i); } }

__global__ __launch_bounds__(1024, 4) void negdict_main(const float* __restrict__ x,
                                                        const float* __restrict__ dict,
                                                        const float* __restrict__ inv_norm,
                                                        float* __restrict__ out) {
    const int pg   = blockIdx.x;
    const int b    = pg >> 6;
    const int pix0 = (pg & 63) << 6;
    const int lane = (int)(threadIdx.x & 63);
    const int wv   = __builtin_amdgcn_readfirstlane((int)(threadIdx.x >> 6));
    const int pix  = pix0 + lane;
    const int n0   = wv * 32;

    const float* __restrict__ xb = x + (size_t)b * C_DIM * HW;

    ACCS(DECL_ACC)
    float sumsq = 0.f;

    for (int kc = 0; kc < C_DIM; kc += 8) {
        const float* __restrict__ xp = xb + (size_t)kc * HW + pix;
        float xk0 = xp[0 * HW];
        float xk1 = xp[1 * HW];
        float xk2 = xp[2 * HW];
        float xk3 = xp[3 * HW];
        float xk4 = xp[4 * HW];
        float xk5 = xp[5 * HW];
        float xk6 = xp[6 * HW];
        float xk7 = xp[7 * HW];
        sumsq = fmaf(xk0, xk0, sumsq);
        sumsq = fmaf(xk1, xk1, sumsq);
        sumsq = fmaf(xk2, xk2, sumsq);
        sumsq = fmaf(xk3, xk3, sumsq);
        sumsq = fmaf(xk4, xk4, sumsq);
        sumsq = fmaf(xk5, xk5, sumsq);
        sumsq = fmaf(xk6, xk6, sumsq);
        sumsq = fmaf(xk7, xk7, sumsq);

        const float* __restrict__ dbase = dict + (size_t)n0 * C_DIM + kc;
        ACCS(ROW_FMA)
    }

    const float* __restrict__ invn = inv_norm + n0;
    float best = -3.0e38f;
    int   bestn = n0;
    ACCS(ARGMAX)

    __shared__ float ls_best[16][64];
    __shared__ int   ls_idx[16][64];
    ls_best[wv][lane] = best;
    ls_idx[wv][lane]  = bestn;
    __syncthreads();

    float fbest = ls_best[0][lane];
    int   fidx  = ls_idx[0][lane];
#pragma unroll
    for (int q = 1; q < 16; ++q) {
        float v  = ls_best[q][lane];
        int   id = ls_idx[q][lane];
        if (v > fbest) { fbest = v; fidx = id; }
    }

    const bool replace = fbest > (-0.25f * sqrtf(sumsq));
    const unsigned long long need_x = __ballot(!replace);

    float* __restrict__ ob = out + (size_t)b * C_DIM * HW;
    const float* __restrict__ drow = dict + (size_t)fidx * C_DIM;

    const int c0 = wv * 32;
#pragma unroll 8
    for (int c = c0; c < c0 + 32; ++c) {
        float v = drow[c];
        if (need_x) {
            float xv = xb[(size_t)c * HW + pix];
            if (!replace) v = xv;
        }
        ob[(size_t)c * HW + pix] = v;
    }
}

extern "C" void kernel_launch(void* const* d_in, const int* in_sizes, int n_in,
                              void* d_out, int out_size, void* d_ws, size_t ws_size,
                              hipStream_t stream) {
    const float* x    = (const float*)d_in[0];
    const float* dict = (const float*)d_in[1];
    float* out        = (float*)d_out;

    const size_t need = (size_t)N_DICT * C_DIM * 2 * sizeof(_Float16) + N_DICT * sizeof(float);
    if (ws_size >= need) {
        _Float16* d1 = (_Float16*)d_ws;
        _Float16* d2 = d1 + (size_t)N_DICT * C_DIM;
        float* invn  = (float*)(d2 + (size_t)N_DICT * C_DIM);
        dict_prep<<<N_DICT, 64, 0, stream>>>(dict, d1, d2, invn);
        negdict_mfma<<<1024, 512, 0, stream>>>(x, dict, d1, d2, invn, out);
    } else {
        float* inv_norm = (float*)d_ws;
        dict_inv_norm<<<N_DICT, 64, 0, stream>>>(dict, inv_norm);
        negdict_main<<<1024, 1024, 0, stream>>>(x, dict, inv_norm, out);
    }
}

// Round 2
// 369.413 us; speedup vs baseline: 4.2134x; 1.3400x over previous
//
#include <hip/hip_runtime.h>
#include <math.h>

#define C_DIM  512   // channels (K of the dot product)
#define N_DICT 512   // dictionary rows
#define HW     4096  // 64*64 pixels per image

typedef _Float16 h8_t __attribute__((ext_vector_type(8)));
typedef _Float16 h4_t __attribute__((ext_vector_type(4)));
typedef float    f4_t __attribute__((ext_vector_type(4)));

#define SCALE_D 16384.0f   // keeps fp16 low-half of dict out of subnormal range
#define SCALE_X 256.0f     // same for x

// ---------------------------------------------------------------------------
// Prologue: inv_norm (scale-folded) + two-way fp16 split of dict (x2^14),
// stored PACKED in MFMA A-fragment order so the main kernel's A-loads are
// one contiguous 1024B wave-load:  elem(rowblk, oct, arow, j) at
// ((rowblk*64 + oct)*16 + arow)*8 + j   (rowblk=row>>4, arow=row&15, oct=ch>>3)
// ---------------------------------------------------------------------------
__global__ __launch_bounds__(64) void dict_prep(const float* __restrict__ dict,
                                                _Float16* __restrict__ d1p,
                                                _Float16* __restrict__ d2p,
                                                float* __restrict__ invn) {
    const int n  = blockIdx.x;
    const int kq = threadIdx.x;             // channel-oct 0..63
    const float* __restrict__ row = dict + n * C_DIM;
    const float4* rp = (const float4*)(row + kq * 8);
    float4 va = rp[0], vb = rp[1];
    float vv[8] = {va.x, va.y, va.z, va.w, vb.x, vb.y, vb.z, vb.w};
    float s = 0.f;
    h8_t h1, h2;
#pragma unroll
    for (int j = 0; j < 8; ++j) {
        float v = vv[j];
        s = fmaf(v, v, s);
        float xs = v * SCALE_D;
        _Float16 a = (_Float16)xs;
        float r = xs - (float)a;
        h1[j] = a;
        h2[j] = (_Float16)r;
    }
    const size_t dest = ((size_t)(n >> 4) * 64 + kq) * 16 + (n & 15); // h8 slot idx
    *(h8_t*)(d1p + dest * 8) = h1;
    *(h8_t*)(d2p + dest * 8) = h2;
#pragma unroll
    for (int off = 32; off > 0; off >>= 1) s += __shfl_down(s, off, 64);
    if (kq == 0) invn[n] = (1.0f / sqrtf(s)) * (1.0f / (SCALE_D * SCALE_X));
}

// ---------------------------------------------------------------------------
// Main MFMA kernel, R2 geometry: grid 2048 = 16 b x 128 groups of 32 pixels,
// 512 thr (8 waves). Wave w -> rows [64w,64w+64) x 32 pix: acc 4rf x 2cf = 32.
// __launch_bounds__(512,4): force <=128 unified regs -> 2 blocks/CU resident.
// K-step 64, x tile [32 pix][272B] (17 slots, stride==1 mod 8 granules ->
// conflict-free ds_read_b128 + 2-way-max ds_write_b64). A-frags from packed
// dict: one contiguous 1KB wave-load each.
// ---------------------------------------------------------------------------
__global__ __launch_bounds__(512, 4) void negdict_mfma2(
        const float* __restrict__ x,
        const float* __restrict__ dict,
        const _Float16* __restrict__ d1p,
        const _Float16* __restrict__ d2p,
        const float* __restrict__ invn,
        float* __restrict__ out) {
    __shared__ __attribute__((aligned(16))) unsigned char lds_x[2][32 * 272];
    __shared__ float ls_best[8][32];
    __shared__ int   ls_idx[8][32];
    __shared__ float ls_ssq[8][64];
    __shared__ int   fin[32];

    const int pg   = blockIdx.x;
    const int b    = pg >> 7;
    const int pix0 = (pg & 127) << 5;       // 32-pixel group base
    const int t    = (int)threadIdx.x;
    const int lane = t & 63;
    const int w    = __builtin_amdgcn_readfirstlane(t >> 6); // 0..7 uniform

    const float* __restrict__ xb = x + (size_t)b * (C_DIM * HW);

    // staging map: thread <-> (pix, kq_local, half): 32*8*2 = 512
    const int spix = lane & 31;
    const int kql  = (w & 3) * 2 + (lane >> 5);   // channel-oct within step 0..7
    const int hf   = w >> 2;                      // half of the oct (4 ch)
    const int choff = kql * 8 + hf * 4;           // channel offset within 64-ch step
    const int wr_hi = spix * 272 + kql * 32 + hf * 8;  // split-hi slot (kql*2)*16
    const int wr_lo = wr_hi + 16;                      // split-lo slot

    // A-frag addressing: lane holds A[row=arow][k=8*akq+j]; packed => +lane*16B
    const int arow = lane & 15;
    const int akq  = lane >> 4;
    const _Float16* __restrict__ a1w = d1p + (size_t)w * 32768 + lane * 8;
    const _Float16* __restrict__ a2w = d2p + (size_t)w * 32768 + lane * 8;

    // B-frag LDS base: p*272 + akq*32 (+ cf*4352 + ks*128 + s*16 compile-time)
    const int rbase_b = (lane & 15) * 272 + akq * 32;

    f4_t acc[4][2];
#pragma unroll
    for (int rf = 0; rf < 4; ++rf)
#pragma unroll
        for (int cf = 0; cf < 2; ++cf)
            acc[rf][cf] = (f4_t){0.f, 0.f, 0.f, 0.f};

    float sumsq = 0.f;

    // stage K-step 0 into buf 0
    {
        const float* xp = xb + (size_t)choff * HW + pix0 + spix;
        float xvv[4] = {xp[0], xp[HW], xp[2 * HW], xp[3 * HW]};
        h4_t p1, p2;
#pragma unroll
        for (int i = 0; i < 4; ++i) {
            float v = xvv[i];
            sumsq = fmaf(v, v, sumsq);
            float xs = v * SCALE_X;
            _Float16 a = (_Float16)xs;
            float r = xs - (float)a;
            p1[i] = a;
            p2[i] = (_Float16)r;
        }
        *(h4_t*)(&lds_x[0][wr_hi]) = p1;
        *(h4_t*)(&lds_x[0][wr_lo]) = p2;
    }
    __syncthreads();

    int cur = 0;
#pragma unroll 1
    for (int step = 0; step < 8; ++step) {
        // prefetch next 64-ch tile (4 coalesced 128B-segment loads)
        float nxt0 = 0.f, nxt1 = 0.f, nxt2 = 0.f, nxt3 = 0.f;
        if (step < 7) {
            const float* xp = xb + (size_t)(step * 64 + 64 + choff) * HW + pix0 + spix;
            nxt0 = xp[0]; nxt1 = xp[HW]; nxt2 = xp[2 * HW]; nxt3 = xp[3 * HW];
        }

        const unsigned char* lb = lds_x[cur];
#pragma unroll
        for (int ks = 0; ks < 2; ++ks) {
            // A frags: 8 contiguous 1KB wave-loads from packed split dict (L2-hot)
            h8_t A1[4], A2[4];
#pragma unroll
            for (int rf = 0; rf < 4; ++rf) {
                const int eo = rf * 8192 + step * 1024 + ks * 512;
                A1[rf] = *(const h8_t*)(a1w + eo);
                A2[rf] = *(const h8_t*)(a2w + eo);
            }
            // B frags: 4 conflict-free ds_read_b128
            h8_t B1[2], B2[2];
#pragma unroll
            for (int cf = 0; cf < 2; ++cf) {
                B1[cf] = *(const h8_t*)(lb + rbase_b + cf * 4352 + ks * 128);
                B2[cf] = *(const h8_t*)(lb + rbase_b + cf * 4352 + ks * 128 + 16);
            }
#pragma unroll
            for (int rf = 0; rf < 4; ++rf) {
#pragma unroll
                for (int cf = 0; cf < 2; ++cf) {
                    acc[rf][cf] = __builtin_amdgcn_mfma_f32_16x16x32_f16(A1[rf], B1[cf], acc[rf][cf], 0, 0, 0);
                    acc[rf][cf] = __builtin_amdgcn_mfma_f32_16x16x32_f16(A1[rf], B2[cf], acc[rf][cf], 0, 0, 0);
                    acc[rf][cf] = __builtin_amdgcn_mfma_f32_16x16x32_f16(A2[rf], B1[cf], acc[rf][cf], 0, 0, 0);
                }
            }
        }

        if (step < 7) {
            unsigned char* lw = lds_x[cur ^ 1];
            float xvv[4] = {nxt0, nxt1, nxt2, nxt3};
            h4_t p1, p2;
#pragma unroll
            for (int i = 0; i < 4; ++i) {
                float v = xvv[i];
                sumsq = fmaf(v, v, sumsq);
                float xs = v * SCALE_X;
                _Float16 a = (_Float16)xs;
                float r = xs - (float)a;
                p1[i] = a;
                p2[i] = (_Float16)r;
            }
            *(h4_t*)(lw + wr_hi) = p1;
            *(h4_t*)(lw + wr_lo) = p2;
        }
        __syncthreads();
        cur ^= 1;
    }

    // ---- per-pixel argmax: lane holds rows w*64 + rf*16 + akq*4 + i, 2 cf-pixels
    float best0 = -3.0e38f, best1 = -3.0e38f;
    int bi0 = 0, bi1 = 0;
    const int rbase = w * 64 + akq * 4;
#pragma unroll
    for (int rf = 0; rf < 4; ++rf) {
#pragma unroll
        for (int i = 0; i < 4; ++i) {
            const int row = rbase + rf * 16 + i;
            const float inv = invn[row];
            float v0 = acc[rf][0][i] * inv;
            float v1 = acc[rf][1][i] * inv;
            if (v0 > best0 || (v0 == best0 && row < bi0)) { best0 = v0; bi0 = row; }
            if (v1 > best1 || (v1 == best1 && row < bi1)) { best1 = v1; bi1 = row; }
        }
    }
#pragma unroll
    for (int off = 16; off <= 32; off <<= 1) {
        float o0 = __shfl_xor(best0, off, 64); int m0 = __shfl_xor(bi0, off, 64);
        float o1 = __shfl_xor(best1, off, 64); int m1 = __shfl_xor(bi1, off, 64);
        if (o0 > best0 || (o0 == best0 && m0 < bi0)) { best0 = o0; bi0 = m0; }
        if (o1 > best1 || (o1 == best1 && m1 < bi1)) { best1 = o1; bi1 = m1; }
    }
    if (akq == 0) {   // lanes 0..15 publish per-wave winners for 32 pixels
        ls_best[w][ 0 + arow] = best0; ls_idx[w][ 0 + arow] = bi0;
        ls_best[w][16 + arow] = best1; ls_idx[w][16 + arow] = bi1;
    }
    ls_ssq[w][lane] = sumsq;
    __syncthreads();

    if (t < 32) {
        const int p = t;
        float fb = ls_best[0][p]; int fi = ls_idx[0][p];
#pragma unroll
        for (int q = 1; q < 8; ++q) {
            float v = ls_best[q][p]; int id = ls_idx[q][p];
            if (v > fb || (v == fb && id < fi)) { fb = v; fi = id; }
        }
        float ss = 0.f;
#pragma unroll
        for (int q = 0; q < 8; ++q) ss += ls_ssq[q][p] + ls_ssq[q][p + 32];
        // apm < 0.625  <=>  sim > -0.25  <=>  fb > -0.25*||x||   (scales folded)
        fin[p] = (fb > (-0.25f * sqrtf(ss))) ? fi : -1;
    }
    __syncthreads();

    // ---- write-out: wave w owns channels [64w, 64w+64), 2 ch x 32 pix / iter
    const int fi = fin[lane & 31];
    const bool rep = fi >= 0;
    const unsigned long long need_x = __ballot(!rep);  // almost always 0
    const float* __restrict__ drow = dict + (size_t)(rep ? fi : 0) * C_DIM;
    const int gpix = pix0 + (lane & 31);
    float* __restrict__ ob = out + (size_t)b * (C_DIM * HW) + gpix;
    const int c0 = w * 64 + (lane >> 5) * 2;
#pragma unroll 4
    for (int i = 0; i < 16; ++i) {
        const int c = c0 + i * 4;
        float2 v = *(const float2*)(drow + c);    // per-lane gather, dict L2-hot
        if (need_x) {
            if (!rep) {
                v.x = xb[(size_t)c * HW + gpix];
                v.y = xb[(size_t)(c + 1) * HW + gpix];
            }
        }
        ob[(size_t)c * HW]       = v.x;           // coalesced 128B segments
        ob[(size_t)(c + 1) * HW] = v.y;
    }
}

// ---------------------------------------------------------------------------
// Fallback path (verified 1556 us kernel) in case workspace is too small.
// ---------------------------------------------------------------------------
__global__ __launch_bounds__(64) void dict_inv_norm(const float* __restrict__ dict,
                                                    float* __restrict__ inv_norm) {
    const int n = blockIdx.x;
    const int lane = threadIdx.x;
    const float* row = dict + n * C_DIM;
    float s = 0.f;
#pragma unroll
    for (int j = 0; j < C_DIM / 64; ++j) {
        float v = row[j * 64 + lane];
        s = fmaf(v, v, s);
    }
#pragma unroll
    for (int off = 32; off > 0; off >>= 1)
        s += __shfl_down(s, off, 64);
    if (lane == 0) inv_norm[n] = 1.0f / sqrtf(s);
}

#define ACCS(F) F(0) F(1) F(2) F(3) F(4) F(5) F(6) F(7) \
                F(8) F(9) F(10) F(11) F(12) F(13) F(14) F(15) \
                F(16) F(17) F(18) F(19) F(20) F(21) F(22) F(23) \
                F(24) F(25) F(26) F(27) F(28) F(29) F(30) F(31)

#define DECL_ACC(i) float acc##i = 0.f;

#define ROW_FMA(i) { const float* __restrict__ dr = dbase + (size_t)(i) * C_DIM; \
    acc##i = fmaf(dr[0], xk0, acc##i); \
    acc##i = fmaf(dr[1], xk1, acc##i); \
    acc##i = fmaf(dr[2], xk2, acc##i); \
    acc##i = fmaf(dr[3], xk3, acc##i); \
    acc##i = fmaf(dr[4], xk4, acc##i); \
    acc##i = fmaf(dr[5], xk5, acc##i); \
    acc##i = fmaf(dr[6], xk6, acc##i); \
    acc##i = fmaf(dr[7], xk7, acc##i); }

#define ARGMAX(i) { float s = acc##i * invn[i]; \
    if (s > best) { best = s; bestn = n0 + (i); } }

__global__ __launch_bounds__(1024, 4) void negdict_main(const float* __restrict__ x,
                                                        const float* __restrict__ dict,
                                                        const float* __restrict__ inv_norm,
                                                        float* __restrict__ out) {
    const int pg   = blockIdx.x;
    const int b    = pg >> 6;
    const int pix0 = (pg & 63) << 6;
    const int lane = (int)(threadIdx.x & 63);
    const int wv   = __builtin_amdgcn_readfirstlane((int)(threadIdx.x >> 6));
    const int pix  = pix0 + lane;
    const int n0   = wv * 32;

    const float* __restrict__ xb = x + (size_t)b * C_DIM * HW;

    ACCS(DECL_ACC)
    float sumsq = 0.f;

    for (int kc = 0; kc < C_DIM; kc += 8) {
        const float* __restrict__ xp = xb + (size_t)kc * HW + pix;
        float xk0 = xp[0 * HW];
        float xk1 = xp[1 * HW];
        float xk2 = xp[2 * HW];
        float xk3 = xp[3 * HW];
        float xk4 = xp[4 * HW];
        float xk5 = xp[5 * HW];
        float xk6 = xp[6 * HW];
        float xk7 = xp[7 * HW];
        sumsq = fmaf(xk0, xk0, sumsq);
        sumsq = fmaf(xk1, xk1, sumsq);
        sumsq = fmaf(xk2, xk2, sumsq);
        sumsq = fmaf(xk3, xk3, sumsq);
        sumsq = fmaf(xk4, xk4, sumsq);
        sumsq = fmaf(xk5, xk5, sumsq);
        sumsq = fmaf(xk6, xk6, sumsq);
        sumsq = fmaf(xk7, xk7, sumsq);

        const float* __restrict__ dbase = dict + (size_t)n0 * C_DIM + kc;
        ACCS(ROW_FMA)
    }

    const float* __restrict__ invn = inv_norm + n0;
    float best = -3.0e38f;
    int   bestn = n0;
    ACCS(ARGMAX)

    __shared__ float ls_best[16][64];
    __shared__ int   ls_idx[16][64];
    ls_best[wv][lane] = best;
    ls_idx[wv][lane]  = bestn;
    __syncthreads();

    float fbest = ls_best[0][lane];
    int   fidx  = ls_idx[0][lane];
#pragma unroll
    for (int q = 1; q < 16; ++q) {
        float v  = ls_best[q][lane];
        int   id = ls_idx[q][lane];
        if (v > fbest) { fbest = v; fidx = id; }
    }

    const bool replace = fbest > (-0.25f * sqrtf(sumsq));
    const unsigned long long need_x = __ballot(!replace);

    float* __restrict__ ob = out + (size_t)b * C_DIM * HW;
    const float* __restrict__ drow = dict + (size_t)fidx * C_DIM;

    const int c0 = wv * 32;
#pragma unroll 8
    for (int c = c0; c < c0 + 32; ++c) {
        float v = drow[c];
        if (need_x) {
            float xv = xb[(size_t)c * HW + pix];
            if (!replace) v = xv;
        }
        ob[(size_t)c * HW + pix] = v;
    }
}

extern "C" void kernel_launch(void* const* d_in, const int* in_sizes, int n_in,
                              void* d_out, int out_size, void* d_ws, size_t ws_size,
                              hipStream_t stream) {
    const float* x    = (const float*)d_in[0];
    const float* dict = (const float*)d_in[1];
    float* out        = (float*)d_out;

    const size_t need = (size_t)N_DICT * C_DIM * 2 * sizeof(_Float16) + N_DICT * sizeof(float);
    if (ws_size >= need) {
        _Float16* d1p = (_Float16*)d_ws;
        _Float16* d2p = d1p + (size_t)N_DICT * C_DIM;
        float* invn   = (float*)(d2p + (size_t)N_DICT * C_DIM);
        dict_prep<<<N_DICT, 64, 0, stream>>>(dict, d1p, d2p, invn);
        negdict_mfma2<<<2048, 512, 0, stream>>>(x, dict, d1p, d2p, invn, out);
    } else {
        float* inv_norm = (float*)d_ws;
        dict_inv_norm<<<N_DICT, 64, 0, stream>>>(dict, inv_norm);
        negdict_main<<<1024, 1024, 0, stream>>>(x, dict, inv_norm, out);
    }
}